// Round 3
// baseline (880.269 us; speedup 1.0000x reference)
//
#include <hip/hip_runtime.h>
#include <hip/hip_fp16.h>
#include <math.h>

#define N_NODES 51200
#define N_EDGES 819200
#define NB 64
#define CAP 64  // max in-degree; Binomial(E,1/N) mean 16, P(>=64) ~ 1e-19

typedef _Float16 half8 __attribute__((ext_vector_type(8)));
typedef __attribute__((ext_vector_type(4))) float float4v;

__device__ __forceinline__ float eluf(float x) {
  return x > 0.f ? x : expm1f(x);
}

// Decode packed edge record {w0 = src|K<<16, w1 = half2(f0,f1)} for corner c.
__device__ __forceinline__ void dec2(int w0, int w1, int c, float& basf, int& Kc) {
  int K = w0 >> 16;  // src < 65536, K <= 18 -> w0 >= 0
  float f0 = __half2float(__ushort_as_half((unsigned short)(w1 & 0xFFFF)));
  float f1 = __half2float(__ushort_as_half((unsigned short)(((unsigned)w1) >> 16)));
  float b0 = (c & 2) ? f0 : 1.f - f0;
  float bv = (c & 1) ? f1 : 1.f - f1;
  Kc = K + (c >> 1) * 5 + (c & 1);
  basf = b0 * bv;
}

// Prep: xcast (N x 7 fp32 -> N x 8 fp16) | W1T | W2T | zero gbuf. Grid 1852.
__global__ __launch_bounds__(256) void prep(const float* __restrict__ x,
                                            const float* __restrict__ W1,
                                            const float* __restrict__ root1,
                                            const float* __restrict__ W2,
                                            const float* __restrict__ root2,
                                            __half* __restrict__ xh,
                                            __half* __restrict__ W1T,
                                            __half* __restrict__ W2T,
                                            float* __restrict__ gbuf) {
  int b = blockIdx.x, tid = threadIdx.x;
  if (b < 1600) {                       // xcast: N*8 = 409600
    int idx = b * 256 + tid;
    int n = idx >> 3, j = idx & 7;
    xh[idx] = __float2half((j < 7) ? x[n * 7 + j] : 0.f);
  } else if (b < 1628) {                // W1T: 32 feats x 224 = 7168
    int idx = (b - 1600) * 256 + tid;
    int o = idx / 224, k = idx - o * 224;
    float v = 0.f;
    if (k < 200) {
      int cell = k >> 3, f = k & 7;
      if (f < 7) v = W1[(cell * 7 + f) * 32 + o];
    } else if (k < 207) {
      v = root1[(k - 200) * 32 + o];
    }
    W1T[idx] = __float2half(v);
  } else if (b < 1836) {                // W2T: 64 feats x 832 = 53248
    int idx = (b - 1628) * 256 + tid;
    int o = idx / 832, k = idx - o * 832;
    float v = (k < 800) ? W2[k * 64 + o] : root2[(k - 800) * 64 + o];
    W2T[idx] = __float2half(v);
  } else {                              // zero gbuf: 64*64 = 4096
    int idx = (b - 1836) * 256 + tid;
    gbuf[idx] = 0.f;
  }
}

// Build dst-CSR with fixed-capacity buckets; 8 edges per thread (8 independent
// atomic chains in flight). cnt doubles as degree.
__global__ __launch_bounds__(256) void scatter_eid(const int* __restrict__ ei,
                                                   const float* __restrict__ pseudo,
                                                   int* __restrict__ cnt,
                                                   int2* __restrict__ bucket) {
  int base = blockIdx.x * 2048 + threadIdx.x;
#pragma unroll
  for (int u = 0; u < 8; u++) {
    int e = base + u * 256;
    int src = ei[e], dst = ei[N_EDGES + e];
    float v0 = pseudo[2 * e] * 4.f;
    float v1 = pseudo[2 * e + 1] * 4.f;
    int lo0 = min(max((int)floorf(v0), 0), 3);
    int lo1 = min(max((int)floorf(v1), 0), 3);
    float f0 = v0 - (float)lo0, f1 = v1 - (float)lo1;
    int K = lo0 * 5 + lo1;  // corners at K, K+1, K+5, K+6
    unsigned short u0 = __half_as_ushort(__float2half(f0));
    unsigned short u1 = __half_as_ushort(__float2half(f1));
    int w0 = src | (K << 16);
    int w1 = (int)((unsigned)u0 | ((unsigned)u1 << 16));
    int slot = atomicAdd(&cnt[dst], 1);
    if (slot < CAP) bucket[(size_t)dst * CAP + slot] = make_int2(w0, w1);
  }
}

// Layer 1 fused. R2 change: Phase A accumulates T in FP32 LDS via native
// ds_add_f32 (atomicAdd on __shared__ float) — fire-and-forget, no read-wait-
// write chain, no ordering requirement between aliasing corner updates.
// (R1's unsafeAtomicAdd(half2) lowered to a CAS loop: 5x regression. R0's
// serialized fp16 RMW chain was the original latency bottleneck.)
// After Phase A: reg-staged in-place f32->f16 convert, then unchanged MFMA:
// h1 = elu( ([T | deg*x] @ [W1;root1]T) * invdeg + b1 ), fp16 out.
#define L1N 16
__global__ __launch_bounds__(256) void fused_l1(const int2* __restrict__ bucket,
                                                const int* __restrict__ cnt,
                                                const unsigned* __restrict__ xh,   // N x 4 dwords
                                                const __half* __restrict__ W1T,
                                                const float* __restrict__ b1,
                                                unsigned short* __restrict__ h1h) {
  __shared__ float T32[L1N * 208];  // 13.3 KB; cells [0,200), append [200,208)
  __shared__ float invdeg_s[L1N];
  int tid = threadIdx.x;
  int n0 = blockIdx.x * L1N;
  for (int idx = tid; idx < L1N * 208; idx += 256) T32[idx] = 0.f;
  if (tid < L1N) invdeg_s[tid] = 1.f / fmaxf((float)cnt[n0 + tid], 1.f);
  __syncthreads();
  // append max(deg,1)*x as f32 at [200..208) (Phase A touches f32 < 200).
  if (tid < L1N * 8) {
    int row = tid >> 3, f = tid & 7;
    int n = n0 + row;
    float dgc = fmaxf((float)cnt[n], 1.f);
    __half hv = ((const __half*)xh)[n * 8 + f];
    T32[row * 208 + 200 + f] = __half2float(hv) * dgc;
  }
  int wv = tid >> 6, l = tid & 63;
  int slot = l >> 4, c = (l >> 2) & 3, p = l & 3;
  int nn = wv * 4 + slot;
  int n = n0 + nn;
  int dg = min(cnt[n], CAP);
  int dmax = dg;
  dmax = max(dmax, __shfl_xor(dmax, 16));
  dmax = max(dmax, __shfl_xor(dmax, 32));
  const int2* bk = bucket + (size_t)n * CAP;
  float* Tr = &T32[nn * 208];
  // pipeline prologue: records for iters 0,1; x-gathers for iter 0.
  int4 ra0 = *(const int4*)(bk + 0);
  int4 rb0 = *(const int4*)(bk + 2);
  int4 ra1 = *(const int4*)(bk + 4);
  int4 rb1 = *(const int4*)(bk + 6);
  unsigned xv0 = xh[(ra0.x & 0xFFFF) * 4 + p];
  unsigned xv1 = xh[(ra0.z & 0xFFFF) * 4 + p];
  unsigned xv2 = xh[(rb0.x & 0xFFFF) * 4 + p];
  unsigned xv3 = xh[(rb0.z & 0xFFFF) * 4 + p];
  for (int j = 0; j < dmax; j += 4) {
    int jp = min(j + 8, CAP - 4);               // records 2 iters ahead
    int4 ra2 = *(const int4*)(bk + jp);
    int4 rb2 = *(const int4*)(bk + jp + 2);
    unsigned nx0 = xh[(ra1.x & 0xFFFF) * 4 + p];  // gathers 1 iter ahead
    unsigned nx1 = xh[(ra1.z & 0xFFFF) * 4 + p];
    unsigned nx2 = xh[(rb1.x & 0xFFFF) * 4 + p];
    unsigned nx3 = xh[(rb1.z & 0xFFFF) * 4 + p];
    bool a0 = j < dg, a1 = j + 1 < dg, a2 = j + 2 < dg, a3 = j + 3 < dg;
    float bf; int Kc;
    if (a0) { dec2(ra0.x, ra0.y, c, bf, Kc);
      float2 hf = __half22float2(*(const __half2*)&xv0);
      atomicAdd(&Tr[Kc * 8 + p * 2 + 0], bf * hf.x);
      atomicAdd(&Tr[Kc * 8 + p * 2 + 1], bf * hf.y); }
    if (a1) { dec2(ra0.z, ra0.w, c, bf, Kc);
      float2 hf = __half22float2(*(const __half2*)&xv1);
      atomicAdd(&Tr[Kc * 8 + p * 2 + 0], bf * hf.x);
      atomicAdd(&Tr[Kc * 8 + p * 2 + 1], bf * hf.y); }
    if (a2) { dec2(rb0.x, rb0.y, c, bf, Kc);
      float2 hf = __half22float2(*(const __half2*)&xv2);
      atomicAdd(&Tr[Kc * 8 + p * 2 + 0], bf * hf.x);
      atomicAdd(&Tr[Kc * 8 + p * 2 + 1], bf * hf.y); }
    if (a3) { dec2(rb0.z, rb0.w, c, bf, Kc);
      float2 hf = __half22float2(*(const __half2*)&xv3);
      atomicAdd(&Tr[Kc * 8 + p * 2 + 0], bf * hf.x);
      atomicAdd(&Tr[Kc * 8 + p * 2 + 1], bf * hf.y); }
    ra0 = ra1; rb0 = rb1; ra1 = ra2; rb1 = rb2;
    xv0 = nx0; xv1 = nx1; xv2 = nx2; xv3 = nx3;
  }
  __syncthreads();
  // In-place f32 -> f16 repack to [16 rows][224 halves] (dword stride 112).
  // All reads reg-staged before the barrier that allows writes.
  unsigned* T16 = (unsigned*)T32;
  {
    int row = tid >> 4, s = tid & 15;   // 14 halves per (row, s)
    float v[14];
#pragma unroll
    for (int i = 0; i < 14; i++) {
      int h = s * 14 + i;
      v[i] = (h < 208) ? T32[row * 208 + h] : 0.f;
    }
    __syncthreads();
#pragma unroll
    for (int i = 0; i < 7; i++) {
      __half2 hv = __floats2half2_rn(v[2 * i], v[2 * i + 1]);
      T16[row * 112 + s * 7 + i] = *(unsigned*)&hv;
    }
  }
  __syncthreads();
  // MFMA: waves 0,1 -> feat tiles 0,1; M=16 nodes, K=224 (7 iters).
  if (wv < 2) {
    int m = l & 15, quad = l >> 4;
    const char* abase = (const char*)T16 + m * 448 + quad * 16;
    const __half* bbase = W1T + (wv * 16 + m) * 224 + quad * 8;
    float4v acc = {0.f, 0.f, 0.f, 0.f};
#pragma unroll
    for (int it = 0; it < 7; it++) {
      half8 af = *(const half8*)(abase + it * 64);
      half8 bf = *(const half8*)(bbase + it * 32);
      acc = __builtin_amdgcn_mfma_f32_16x16x32_f16(af, bf, acc, 0, 0, 0);
    }
    int feat = wv * 16 + m;
    float bb = b1[feat];
#pragma unroll
    for (int r = 0; r < 4; r++) {
      int row = quad * 4 + r;
      float v = eluf(acc[r] * invdeg_s[row] + bb);
      h1h[(size_t)(n0 + row) * 32 + feat] = __half_as_ushort(__float2half(v));
    }
  }
}

// Layer 2 fused. Same R2 restructure: FP32 LDS accumulate via ds_add_f32,
// reg-staged in-place f32->f16 convert, then unchanged MFMA epilogue that
// also pool-reduces elu(h2) into gbuf (one atomicAdd per block,feat).
#define L2N 16
__global__ __launch_bounds__(256) void fused_l2(const int2* __restrict__ bucket,
                                                const int* __restrict__ cnt,
                                                const unsigned* __restrict__ h1hu,  // N x 16 dwords
                                                const __half* __restrict__ W2T,
                                                const float* __restrict__ b2,
                                                float* __restrict__ gbuf) {
  __shared__ float T32[L2N * 836];  // 53.5 KB; cells [0,800), append [800,832), pad
  __shared__ float invdeg_s[L2N];
  int tid = threadIdx.x;
  int n0 = blockIdx.x * L2N;
  for (int idx = tid; idx < L2N * 836; idx += 256) T32[idx] = 0.f;
  if (tid < L2N) invdeg_s[tid] = 1.f / fmaxf((float)cnt[n0 + tid], 1.f);
  __syncthreads();
  // append max(deg,1)*h1 as f32 at [800..832) (Phase A touches f32 < 800).
  {
    int row = tid >> 4, p = tid & 15;
    int n = n0 + row;
    float dgc = fmaxf((float)cnt[n], 1.f);
    unsigned hv = h1hu[(size_t)n * 16 + p];
    float2 hf = __half22float2(*(const __half2*)&hv);
    T32[row * 836 + 800 + 2 * p + 0] = hf.x * dgc;
    T32[row * 836 + 800 + 2 * p + 1] = hf.y * dgc;
  }
  int wv = tid >> 6, l = tid & 63;
  int slot = l >> 4, c = (l >> 2) & 3, q = l & 3;
  int nn = wv * 4 + slot;
  int n = n0 + nn;
  int dg = min(cnt[n], CAP);
  int dmax = dg;
  dmax = max(dmax, __shfl_xor(dmax, 16));
  dmax = max(dmax, __shfl_xor(dmax, 32));
  const int2* bk = bucket + (size_t)n * CAP;
  float* Tr = &T32[nn * 836];
  const unsigned* h1q = h1hu + q * 4;
  // pipeline prologue: records for iters 0,1; h1-gathers for iter 0.
  int4 ra0 = *(const int4*)(bk + 0);
  int4 rb0 = *(const int4*)(bk + 2);
  int4 ra1 = *(const int4*)(bk + 4);
  int4 rb1 = *(const int4*)(bk + 6);
  int4 hv0 = *(const int4*)(h1q + (size_t)(ra0.x & 0xFFFF) * 16);
  int4 hv1 = *(const int4*)(h1q + (size_t)(ra0.z & 0xFFFF) * 16);
  int4 hv2 = *(const int4*)(h1q + (size_t)(rb0.x & 0xFFFF) * 16);
  int4 hv3 = *(const int4*)(h1q + (size_t)(rb0.z & 0xFFFF) * 16);
  for (int j = 0; j < dmax; j += 4) {
    int jp = min(j + 8, CAP - 4);               // records 2 iters ahead
    int4 ra2 = *(const int4*)(bk + jp);
    int4 rb2 = *(const int4*)(bk + jp + 2);
    int4 nh0 = *(const int4*)(h1q + (size_t)(ra1.x & 0xFFFF) * 16);  // 1 ahead
    int4 nh1 = *(const int4*)(h1q + (size_t)(ra1.z & 0xFFFF) * 16);
    int4 nh2 = *(const int4*)(h1q + (size_t)(rb1.x & 0xFFFF) * 16);
    int4 nh3 = *(const int4*)(h1q + (size_t)(rb1.z & 0xFFFF) * 16);
    bool a0 = j < dg, a1 = j + 1 < dg, a2 = j + 2 < dg, a3 = j + 3 < dg;
    float bf; int Kc;
    if (a0) { dec2(ra0.x, ra0.y, c, bf, Kc);
      const __half2* hh = (const __half2*)&hv0;
      float* tp = &Tr[Kc * 32 + q * 8];
#pragma unroll
      for (int i = 0; i < 4; i++) {
        float2 hf = __half22float2(hh[i]);
        atomicAdd(&tp[2 * i + 0], bf * hf.x);
        atomicAdd(&tp[2 * i + 1], bf * hf.y);
      } }
    if (a1) { dec2(ra0.z, ra0.w, c, bf, Kc);
      const __half2* hh = (const __half2*)&hv1;
      float* tp = &Tr[Kc * 32 + q * 8];
#pragma unroll
      for (int i = 0; i < 4; i++) {
        float2 hf = __half22float2(hh[i]);
        atomicAdd(&tp[2 * i + 0], bf * hf.x);
        atomicAdd(&tp[2 * i + 1], bf * hf.y);
      } }
    if (a2) { dec2(rb0.x, rb0.y, c, bf, Kc);
      const __half2* hh = (const __half2*)&hv2;
      float* tp = &Tr[Kc * 32 + q * 8];
#pragma unroll
      for (int i = 0; i < 4; i++) {
        float2 hf = __half22float2(hh[i]);
        atomicAdd(&tp[2 * i + 0], bf * hf.x);
        atomicAdd(&tp[2 * i + 1], bf * hf.y);
      } }
    if (a3) { dec2(rb0.z, rb0.w, c, bf, Kc);
      const __half2* hh = (const __half2*)&hv3;
      float* tp = &Tr[Kc * 32 + q * 8];
#pragma unroll
      for (int i = 0; i < 4; i++) {
        float2 hf = __half22float2(hh[i]);
        atomicAdd(&tp[2 * i + 0], bf * hf.x);
        atomicAdd(&tp[2 * i + 1], bf * hf.y);
      } }
    ra0 = ra1; rb0 = rb1; ra1 = ra2; rb1 = rb2;
    hv0 = nh0; hv1 = nh1; hv2 = nh2; hv3 = nh3;
  }
  __syncthreads();
  // In-place f32 -> f16 repack to [16 rows][840 halves] (dword stride 420,
  // halves [0,832) valid; pad dwords 416..419 never read by MFMA).
  // All reads reg-staged before the barrier that allows writes.
  unsigned* T16 = (unsigned*)T32;
  {
    int row = tid >> 4, s = tid & 15;   // 52 halves per (row, s)
    float v[52];
#pragma unroll
    for (int i = 0; i < 52; i++) v[i] = T32[row * 836 + s * 52 + i];
    __syncthreads();
#pragma unroll
    for (int i = 0; i < 26; i++) {
      __half2 hv = __floats2half2_rn(v[2 * i], v[2 * i + 1]);
      T16[row * 420 + s * 26 + i] = *(unsigned*)&hv;
    }
  }
  __syncthreads();
  // MFMA: wave wv -> feats [wv*16, wv*16+16), K=832 (26 iters).
  int m = l & 15, quad = l >> 4;
  const char* abase = (const char*)T16 + m * 1680 + quad * 16;
  const __half* bbase = W2T + (size_t)(wv * 16 + m) * 832 + quad * 8;
  float4v acc = {0.f, 0.f, 0.f, 0.f};
  for (int it = 0; it < 26; it++) {
    half8 af = *(const half8*)(abase + it * 64);
    half8 bf = *(const half8*)(bbase + it * 32);
    acc = __builtin_amdgcn_mfma_f32_16x16x32_f16(af, bf, acc, 0, 0, 0);
  }
  int feat = wv * 16 + m;
  float bb = b2[feat];
  float psum = 0.f;
#pragma unroll
  for (int r = 0; r < 4; r++) {
    int node = quad * 4 + r;
    psum += eluf(acc[r] * invdeg_s[node] + bb);
  }
  // reduce over quad (nodes) -> full 16-node sum per feat; 800 nodes per
  // group and 800 % L2N == 0, so the whole block is in one group.
  psum += __shfl_xor(psum, 16);
  psum += __shfl_xor(psum, 32);
  if (l < 16) {
    int g = n0 / 800;
    atomicAdd(&gbuf[g * 64 + feat], psum);
  }
}

// FC(64->30) + log_softmax on pooled sums. gbuf holds per-group SUM of elu(h2);
// divide by slice count here. One block (64 thr) per group; lanes 0..29 active.
__global__ __launch_bounds__(64) void fc_ls(const float* __restrict__ gbuf,
                                            const int* __restrict__ slices,
                                            const float* __restrict__ fcw,
                                            const float* __restrict__ fcb,
                                            float* __restrict__ out) {
  int g = blockIdx.x;
  int l = threadIdx.x;
  float scale = 1.f / fmaxf((float)(slices[g + 1] - slices[g]), 1.f);
  float logit = -INFINITY;
  if (l < 30) {
    float acc = fcb[l];
    for (int i = 0; i < 64; i++) acc += gbuf[g * 64 + i] * scale * fcw[i * 30 + l];
    logit = acc;
  }
  float m = logit;
  for (int off = 16; off; off >>= 1) m = fmaxf(m, __shfl_xor(m, off, 32));
  float e = (l < 30) ? expf(logit - m) : 0.f;
  for (int off = 16; off; off >>= 1) e += __shfl_xor(e, off, 32);
  if (l < 30) out[g * 30 + l] = logit - m - logf(e);
}

extern "C" void kernel_launch(void* const* d_in, const int* in_sizes, int n_in,
                              void* d_out, int out_size, void* d_ws, size_t ws_size,
                              hipStream_t stream) {
  const float* x      = (const float*)d_in[0];
  const int*   ei     = (const int*)d_in[1];
  const float* pseudo = (const float*)d_in[2];
  const int*   slices = (const int*)d_in[3];
  const float* W1     = (const float*)d_in[4];
  const float* root1  = (const float*)d_in[5];
  const float* b1     = (const float*)d_in[6];
  const float* W2     = (const float*)d_in[7];
  const float* root2  = (const float*)d_in[8];
  const float* b2     = (const float*)d_in[9];
  const float* fcw    = (const float*)d_in[10];
  const float* fcb    = (const float*)d_in[11];
  float* out = (float*)d_out;

  char* ws = (char*)d_ws;
  int*      cnt    = (int*)ws;                                    // N ints
  int2*     bucket = (int2*)(cnt + N_NODES);                      // N*CAP int2 (26.2 MB)
  unsigned* h1h    = (unsigned*)(bucket + (size_t)N_NODES * CAP); // N*16 dwords (fp16 h1)
  float*    gbuf   = (float*)(h1h + (size_t)N_NODES * 16);        // 64*64 fp32
  unsigned* xh     = (unsigned*)(gbuf + 64 * 64);                 // N*4 dwords (fp16 x)
  __half*   W1T    = (__half*)(xh + (size_t)N_NODES * 4);         // 32*224
  __half*   W2T    = W1T + 32 * 224;                              // 64*832

  hipMemsetAsync(cnt, 0, N_NODES * sizeof(int), stream);

  prep<<<1852, 256, 0, stream>>>(x, W1, root1, W2, root2,
                                 (__half*)xh, W1T, W2T, gbuf);
  scatter_eid<<<N_EDGES / 2048, 256, 0, stream>>>(ei, pseudo, cnt, bucket);
  fused_l1<<<N_NODES / L1N, 256, 0, stream>>>(bucket, cnt, xh, W1T, b1,
                                              (unsigned short*)h1h);
  fused_l2<<<N_NODES / L2N, 256, 0, stream>>>(bucket, cnt, h1h, W2T, b2, gbuf);
  fc_ls<<<NB, 64, 0, stream>>>(gbuf, slices, fcw, fcb, out);
}

// Round 4
// 297.859 us; speedup vs baseline: 2.9553x; 2.9553x over previous
//
#include <hip/hip_runtime.h>
#include <hip/hip_fp16.h>
#include <math.h>

#define N_NODES 51200
#define N_EDGES 819200
#define NB 64
#define CAP 64  // max in-degree; Binomial(E,1/N) mean 16, P(>=64) ~ 1e-19

typedef _Float16 half8 __attribute__((ext_vector_type(8)));
typedef __attribute__((ext_vector_type(4))) float float4v;

__device__ __forceinline__ float eluf(float x) {
  return x > 0.f ? x : expm1f(x);
}

__device__ __forceinline__ int h2i(__half2 v) { union { __half2 h; int i; } u; u.h = v; return u.i; }
__device__ __forceinline__ __half2 i2h(int v) { union { int i; __half2 h; } u; u.i = v; return u.h; }

// Corner weight for this lane's cell given edge record (w0 = src|K<<16,
// w1 = half2(f0,f1)). Cells K, K+1, K+5, K+6 get (1-f0)(1-f1), (1-f0)f1,
// f0(1-f1), f0*f1; every other cell gets 0. Branch-free select.
#define CORNER_W(rw0, rw1, cell, wh_out) do {                                  \
  int K_ = (rw0) >> 16;                                                        \
  unsigned wu_ = (unsigned)(rw1);                                              \
  float f0_ = __half2float(__ushort_as_half((unsigned short)(wu_ & 0xFFFF)));  \
  float f1_ = __half2float(__ushort_as_half((unsigned short)(wu_ >> 16)));     \
  int d_ = (cell) - K_;                                                        \
  bool c0_ = d_ == 0, c1_ = d_ == 1, c5_ = d_ == 5, c6_ = d_ == 6;             \
  float wa_ = (c0_ || c1_) ? (1.f - f0_) : f0_;                                \
  float wb_ = (c0_ || c5_) ? (1.f - f1_) : f1_;                                \
  float w_ = (c0_ || c1_ || c5_ || c6_) ? wa_ * wb_ : 0.f;                     \
  wh_out = __float2half2_rn(w_);                                               \
} while (0)

// Prep: xcast (N x 7 fp32 -> N x 8 fp16) | W1T | W2T | zero gbuf. Grid 1852.
__global__ __launch_bounds__(256) void prep(const float* __restrict__ x,
                                            const float* __restrict__ W1,
                                            const float* __restrict__ root1,
                                            const float* __restrict__ W2,
                                            const float* __restrict__ root2,
                                            __half* __restrict__ xh,
                                            __half* __restrict__ W1T,
                                            __half* __restrict__ W2T,
                                            float* __restrict__ gbuf) {
  int b = blockIdx.x, tid = threadIdx.x;
  if (b < 1600) {                       // xcast: N*8 = 409600
    int idx = b * 256 + tid;
    int n = idx >> 3, j = idx & 7;
    xh[idx] = __float2half((j < 7) ? x[n * 7 + j] : 0.f);
  } else if (b < 1628) {                // W1T: 32 feats x 224 = 7168
    int idx = (b - 1600) * 256 + tid;
    int o = idx / 224, k = idx - o * 224;
    float v = 0.f;
    if (k < 200) {
      int cell = k >> 3, f = k & 7;
      if (f < 7) v = W1[(cell * 7 + f) * 32 + o];
    } else if (k < 207) {
      v = root1[(k - 200) * 32 + o];
    }
    W1T[idx] = __float2half(v);
  } else if (b < 1836) {                // W2T: 64 feats x 832 = 53248
    int idx = (b - 1628) * 256 + tid;
    int o = idx / 832, k = idx - o * 832;
    float v = (k < 800) ? W2[k * 64 + o] : root2[(k - 800) * 64 + o];
    W2T[idx] = __float2half(v);
  } else {                              // zero gbuf: 64*64 = 4096
    int idx = (b - 1836) * 256 + tid;
    gbuf[idx] = 0.f;
  }
}

// Build dst-CSR with fixed-capacity buckets; 8 edges per thread (8 independent
// atomic chains in flight). cnt doubles as degree.
__global__ __launch_bounds__(256) void scatter_eid(const int* __restrict__ ei,
                                                   const float* __restrict__ pseudo,
                                                   int* __restrict__ cnt,
                                                   int2* __restrict__ bucket) {
  int base = blockIdx.x * 2048 + threadIdx.x;
#pragma unroll
  for (int u = 0; u < 8; u++) {
    int e = base + u * 256;
    int src = ei[e], dst = ei[N_EDGES + e];
    float v0 = pseudo[2 * e] * 4.f;
    float v1 = pseudo[2 * e + 1] * 4.f;
    int lo0 = min(max((int)floorf(v0), 0), 3);
    int lo1 = min(max((int)floorf(v1), 0), 3);
    float f0 = v0 - (float)lo0, f1 = v1 - (float)lo1;
    int K = lo0 * 5 + lo1;  // corners at K, K+1, K+5, K+6
    unsigned short u0 = __half_as_ushort(__float2half(f0));
    unsigned short u1 = __half_as_ushort(__float2half(f1));
    int w0 = src | (K << 16);
    int w1 = (int)((unsigned)u0 | ((unsigned)u1 << 16));
    int slot = atomicAdd(&cnt[dst], 1);
    if (slot < CAP) bucket[(size_t)dst * CAP + slot] = make_int2(w0, w1);
  }
}

// Layer 1 fused. R3: cell-parallel REGISTER accumulation (no LDS in the edge
// loop). Lane = (node-half u, cell<25); per edge all cell-lanes compute the
// corner weight (0 for 21 of 25 cells) and fma into 4 half2 regs. No RMW
// chain, no atomics. Wave = 2 nodes in parallel, 2 sequential passes.
// Pipeline (from R0): records 2 blocks (8 edges) ahead, x-gathers 1 block
// (4 edges) ahead. Then one LDS write per lane and the unchanged MFMA:
// h1 = elu( ([T | deg*x] @ [W1;root1]T) * invdeg + b1 ), fp16 out.
#define L1N 16
__global__ __launch_bounds__(256) void fused_l1(const int2* __restrict__ bucket,
                                                const int* __restrict__ cnt,
                                                const unsigned* __restrict__ xh,   // N x 4 dwords
                                                const __half* __restrict__ W1T,
                                                const float* __restrict__ b1,
                                                unsigned short* __restrict__ h1h) {
  __shared__ unsigned T16[L1N * 112];  // 7.2 KB; [row][112 dwords]
  __shared__ float invdeg_s[L1N];
  int tid = threadIdx.x;
  int n0 = blockIdx.x * L1N;
  if (tid < L1N) invdeg_s[tid] = 1.f / fmaxf((float)cnt[n0 + tid], 1.f);
  // zero pad dwords 104..111 (read by MFMA K-range, never written below)
  if (tid < 128) T16[(tid >> 3) * 112 + 104 + (tid & 7)] = 0u;
  // append max(deg,1)*x at dwords 100..103 (cells occupy dwords < 100).
  if (tid < L1N * 4) {
    int row = tid >> 2, p = tid & 3;
    int n = n0 + row;
    float dgc = fmaxf((float)cnt[n], 1.f);
    unsigned xv = xh[n * 4 + p];
    __half2 h = __hmul2(*(const __half2*)&xv, __float2half2_rn(dgc));
    T16[row * 112 + 100 + p] = *(unsigned*)&h;
  }
  int wv = tid >> 6, l = tid & 63;
  int u = l >> 5;          // node half
  int cell = l & 31;       // active < 25 (cells 25..31 always get w=0)
  const int4* x4 = (const int4*)xh;
#pragma unroll
  for (int ps = 0; ps < 2; ps++) {
    int row = wv * 4 + ps * 2 + u;
    int n = n0 + row;
    int dg = min(cnt[n], CAP);
    int dmax = max(dg, __shfl_xor(dg, 32));
    const int4* bk4 = (const int4*)(bucket + (size_t)n * CAP);
    __half2 acc0 = i2h(0), acc1 = i2h(0), acc2 = i2h(0), acc3 = i2h(0);
    // prologue: record blocks for edges 0-3, 4-7; gathers for edges 0-3.
    int4 ra0 = bk4[0], rb0 = bk4[1];
    int4 ra1 = bk4[2], rb1 = bk4[3];
    int4 g0 = x4[ra0.x & 0xFFFF];
    int4 g1 = x4[ra0.z & 0xFFFF];
    int4 g2 = x4[rb0.x & 0xFFFF];
    int4 g3 = x4[rb0.z & 0xFFFF];
    for (int j = 0; j < dmax; j += 4) {
      int jp = min(j + 8, CAP - 4);
      int4 ra2 = bk4[jp >> 1], rb2 = bk4[(jp >> 1) + 1];
      int4 ng0 = x4[ra1.x & 0xFFFF];
      int4 ng1 = x4[ra1.z & 0xFFFF];
      int4 ng2 = x4[rb1.x & 0xFFFF];
      int4 ng3 = x4[rb1.z & 0xFFFF];
      __half2 wh;
      if (j < dg) { CORNER_W(ra0.x, ra0.y, cell, wh);
        acc0 = __hfma2(wh, i2h(g0.x), acc0); acc1 = __hfma2(wh, i2h(g0.y), acc1);
        acc2 = __hfma2(wh, i2h(g0.z), acc2); acc3 = __hfma2(wh, i2h(g0.w), acc3); }
      if (j + 1 < dg) { CORNER_W(ra0.z, ra0.w, cell, wh);
        acc0 = __hfma2(wh, i2h(g1.x), acc0); acc1 = __hfma2(wh, i2h(g1.y), acc1);
        acc2 = __hfma2(wh, i2h(g1.z), acc2); acc3 = __hfma2(wh, i2h(g1.w), acc3); }
      if (j + 2 < dg) { CORNER_W(rb0.x, rb0.y, cell, wh);
        acc0 = __hfma2(wh, i2h(g2.x), acc0); acc1 = __hfma2(wh, i2h(g2.y), acc1);
        acc2 = __hfma2(wh, i2h(g2.z), acc2); acc3 = __hfma2(wh, i2h(g2.w), acc3); }
      if (j + 3 < dg) { CORNER_W(rb0.z, rb0.w, cell, wh);
        acc0 = __hfma2(wh, i2h(g3.x), acc0); acc1 = __hfma2(wh, i2h(g3.y), acc1);
        acc2 = __hfma2(wh, i2h(g3.z), acc2); acc3 = __hfma2(wh, i2h(g3.w), acc3); }
      ra0 = ra1; rb0 = rb1; ra1 = ra2; rb1 = rb2;
      g0 = ng0; g1 = ng1; g2 = ng2; g3 = ng3;
    }
    if (cell < 25) {
      unsigned* dst = &T16[row * 112 + cell * 4];
      *(int4*)dst = make_int4(h2i(acc0), h2i(acc1), h2i(acc2), h2i(acc3));
    }
  }
  __syncthreads();
  // MFMA: waves 0,1 -> feat tiles 0,1; M=16 nodes, K=224 (7 iters).
  if (wv < 2) {
    int m = l & 15, quad = l >> 4;
    const char* abase = (const char*)T16 + m * 448 + quad * 16;
    const __half* bbase = W1T + (wv * 16 + m) * 224 + quad * 8;
    float4v acc = {0.f, 0.f, 0.f, 0.f};
#pragma unroll
    for (int it = 0; it < 7; it++) {
      half8 af = *(const half8*)(abase + it * 64);
      half8 bf = *(const half8*)(bbase + it * 32);
      acc = __builtin_amdgcn_mfma_f32_16x16x32_f16(af, bf, acc, 0, 0, 0);
    }
    int feat = wv * 16 + m;
    float bb = b1[feat];
#pragma unroll
    for (int r = 0; r < 4; r++) {
      int row = quad * 4 + r;
      float v = eluf(acc[r] * invdeg_s[row] + bb);
      h1h[(size_t)(n0 + row) * 32 + feat] = __half_as_ushort(__float2half(v));
    }
  }
}

// Layer 2 fused. Same R3 cell-parallel register scheme: whole wave per node
// (lane = cell<25 x feat-half, 8 half2 accs = 16 of 32 in-feats), 4 nodes
// sequential per wave. No LDS in the edge loop; one 32B write per lane per
// node. MFMA epilogue (unchanged) computes elu rows AND pool-reduces into
// gbuf via one atomicAdd per (block, feat). h2 never materialized.
#define L2N 16
__global__ __launch_bounds__(256) void fused_l2(const int2* __restrict__ bucket,
                                                const int* __restrict__ cnt,
                                                const unsigned* __restrict__ h1hu,  // N x 16 dwords
                                                const __half* __restrict__ W2T,
                                                const float* __restrict__ b2,
                                                float* __restrict__ gbuf) {
  __shared__ unsigned T16[L2N * 420];  // 26.9 KB; [row][420 dwords]
  __shared__ float invdeg_s[L2N];
  int tid = threadIdx.x;
  int n0 = blockIdx.x * L2N;
  if (tid < L2N) invdeg_s[tid] = 1.f / fmaxf((float)cnt[n0 + tid], 1.f);
  // append max(deg,1)*h1 at dwords 400..415 (cells occupy dwords < 400).
  {
    int row = tid >> 4, p = tid & 15;
    int n = n0 + row;
    float dgc = fmaxf((float)cnt[n], 1.f);
    unsigned hv = h1hu[(size_t)n * 16 + p];
    __half2 h = __hmul2(*(const __half2*)&hv, __float2half2_rn(dgc));
    T16[row * 420 + 400 + p] = *(unsigned*)&h;
  }
  int wv = tid >> 6, l = tid & 63;
  int h = l >> 5;          // feat half: feats [h*16, h*16+16)
  int cell = l & 31;       // active < 25
  const int4* h4 = (const int4*)h1hu;  // h1 row n = h4[n*4 .. n*4+4)
#pragma unroll 1
  for (int s = 0; s < 4; s++) {
    int row = wv * 4 + s;
    int n = n0 + row;
    int dg = min(cnt[n], CAP);
    const int4* bk4 = (const int4*)(bucket + (size_t)n * CAP);
    __half2 acc0 = i2h(0), acc1 = i2h(0), acc2 = i2h(0), acc3 = i2h(0);
    __half2 acc4 = i2h(0), acc5 = i2h(0), acc6 = i2h(0), acc7 = i2h(0);
    // prologue: record blocks for edges 0-3, 4-7; gathers for edges 0-3.
    int4 ra0 = bk4[0], rb0 = bk4[1];
    int4 ra1 = bk4[2], rb1 = bk4[3];
    int b0 = (ra0.x & 0xFFFF) * 4 + h * 2;
    int b1i = (ra0.z & 0xFFFF) * 4 + h * 2;
    int b2i = (rb0.x & 0xFFFF) * 4 + h * 2;
    int b3 = (rb0.z & 0xFFFF) * 4 + h * 2;
    int4 g0a = h4[b0], g0b = h4[b0 + 1];
    int4 g1a = h4[b1i], g1b = h4[b1i + 1];
    int4 g2a = h4[b2i], g2b = h4[b2i + 1];
    int4 g3a = h4[b3], g3b = h4[b3 + 1];
    for (int j = 0; j < dg; j += 4) {
      int jp = min(j + 8, CAP - 4);
      int4 ra2 = bk4[jp >> 1], rb2 = bk4[(jp >> 1) + 1];
      int nb0 = (ra1.x & 0xFFFF) * 4 + h * 2;
      int nb1 = (ra1.z & 0xFFFF) * 4 + h * 2;
      int nb2 = (rb1.x & 0xFFFF) * 4 + h * 2;
      int nb3 = (rb1.z & 0xFFFF) * 4 + h * 2;
      int4 n0a = h4[nb0], n0b = h4[nb0 + 1];
      int4 n1a = h4[nb1], n1b = h4[nb1 + 1];
      int4 n2a = h4[nb2], n2b = h4[nb2 + 1];
      int4 n3a = h4[nb3], n3b = h4[nb3 + 1];
      __half2 wh;
      if (j < dg) { CORNER_W(ra0.x, ra0.y, cell, wh);
        acc0 = __hfma2(wh, i2h(g0a.x), acc0); acc1 = __hfma2(wh, i2h(g0a.y), acc1);
        acc2 = __hfma2(wh, i2h(g0a.z), acc2); acc3 = __hfma2(wh, i2h(g0a.w), acc3);
        acc4 = __hfma2(wh, i2h(g0b.x), acc4); acc5 = __hfma2(wh, i2h(g0b.y), acc5);
        acc6 = __hfma2(wh, i2h(g0b.z), acc6); acc7 = __hfma2(wh, i2h(g0b.w), acc7); }
      if (j + 1 < dg) { CORNER_W(ra0.z, ra0.w, cell, wh);
        acc0 = __hfma2(wh, i2h(g1a.x), acc0); acc1 = __hfma2(wh, i2h(g1a.y), acc1);
        acc2 = __hfma2(wh, i2h(g1a.z), acc2); acc3 = __hfma2(wh, i2h(g1a.w), acc3);
        acc4 = __hfma2(wh, i2h(g1b.x), acc4); acc5 = __hfma2(wh, i2h(g1b.y), acc5);
        acc6 = __hfma2(wh, i2h(g1b.z), acc6); acc7 = __hfma2(wh, i2h(g1b.w), acc7); }
      if (j + 2 < dg) { CORNER_W(rb0.x, rb0.y, cell, wh);
        acc0 = __hfma2(wh, i2h(g2a.x), acc0); acc1 = __hfma2(wh, i2h(g2a.y), acc1);
        acc2 = __hfma2(wh, i2h(g2a.z), acc2); acc3 = __hfma2(wh, i2h(g2a.w), acc3);
        acc4 = __hfma2(wh, i2h(g2b.x), acc4); acc5 = __hfma2(wh, i2h(g2b.y), acc5);
        acc6 = __hfma2(wh, i2h(g2b.z), acc6); acc7 = __hfma2(wh, i2h(g2b.w), acc7); }
      if (j + 3 < dg) { CORNER_W(rb0.z, rb0.w, cell, wh);
        acc0 = __hfma2(wh, i2h(g3a.x), acc0); acc1 = __hfma2(wh, i2h(g3a.y), acc1);
        acc2 = __hfma2(wh, i2h(g3a.z), acc2); acc3 = __hfma2(wh, i2h(g3a.w), acc3);
        acc4 = __hfma2(wh, i2h(g3b.x), acc4); acc5 = __hfma2(wh, i2h(g3b.y), acc5);
        acc6 = __hfma2(wh, i2h(g3b.z), acc6); acc7 = __hfma2(wh, i2h(g3b.w), acc7); }
      ra0 = ra1; rb0 = rb1; ra1 = ra2; rb1 = rb2;
      g0a = n0a; g0b = n0b; g1a = n1a; g1b = n1b;
      g2a = n2a; g2b = n2b; g3a = n3a; g3b = n3b;
    }
    if (cell < 25) {
      unsigned* dst = &T16[row * 420 + cell * 16 + h * 8];
      *(int4*)dst = make_int4(h2i(acc0), h2i(acc1), h2i(acc2), h2i(acc3));
      *(int4*)(dst + 4) = make_int4(h2i(acc4), h2i(acc5), h2i(acc6), h2i(acc7));
    }
  }
  __syncthreads();
  // MFMA: wave wv -> feats [wv*16, wv*16+16), K=832 (26 iters).
  int m = l & 15, quad = l >> 4;
  const char* abase = (const char*)T16 + m * 1680 + quad * 16;
  const __half* bbase = W2T + (size_t)(wv * 16 + m) * 832 + quad * 8;
  float4v acc = {0.f, 0.f, 0.f, 0.f};
  for (int it = 0; it < 26; it++) {
    half8 af = *(const half8*)(abase + it * 64);
    half8 bf = *(const half8*)(bbase + it * 32);
    acc = __builtin_amdgcn_mfma_f32_16x16x32_f16(af, bf, acc, 0, 0, 0);
  }
  int feat = wv * 16 + m;
  float bb = b2[feat];
  float psum = 0.f;
#pragma unroll
  for (int r = 0; r < 4; r++) {
    int node = quad * 4 + r;
    psum += eluf(acc[r] * invdeg_s[node] + bb);
  }
  // reduce over quad (nodes) -> full 16-node sum per feat; 800 nodes per
  // group and 800 % L2N == 0, so the whole block is in one group.
  psum += __shfl_xor(psum, 16);
  psum += __shfl_xor(psum, 32);
  if (l < 16) {
    int g = n0 / 800;
    atomicAdd(&gbuf[g * 64 + feat], psum);
  }
}

// FC(64->30) + log_softmax on pooled sums. gbuf holds per-group SUM of elu(h2);
// divide by slice count here. One block (64 thr) per group; lanes 0..29 active.
__global__ __launch_bounds__(64) void fc_ls(const float* __restrict__ gbuf,
                                            const int* __restrict__ slices,
                                            const float* __restrict__ fcw,
                                            const float* __restrict__ fcb,
                                            float* __restrict__ out) {
  int g = blockIdx.x;
  int l = threadIdx.x;
  float scale = 1.f / fmaxf((float)(slices[g + 1] - slices[g]), 1.f);
  float logit = -INFINITY;
  if (l < 30) {
    float acc = fcb[l];
    for (int i = 0; i < 64; i++) acc += gbuf[g * 64 + i] * scale * fcw[i * 30 + l];
    logit = acc;
  }
  float m = logit;
  for (int off = 16; off; off >>= 1) m = fmaxf(m, __shfl_xor(m, off, 32));
  float e = (l < 30) ? expf(logit - m) : 0.f;
  for (int off = 16; off; off >>= 1) e += __shfl_xor(e, off, 32);
  if (l < 30) out[g * 30 + l] = logit - m - logf(e);
}

extern "C" void kernel_launch(void* const* d_in, const int* in_sizes, int n_in,
                              void* d_out, int out_size, void* d_ws, size_t ws_size,
                              hipStream_t stream) {
  const float* x      = (const float*)d_in[0];
  const int*   ei     = (const int*)d_in[1];
  const float* pseudo = (const float*)d_in[2];
  const int*   slices = (const int*)d_in[3];
  const float* W1     = (const float*)d_in[4];
  const float* root1  = (const float*)d_in[5];
  const float* b1     = (const float*)d_in[6];
  const float* W2     = (const float*)d_in[7];
  const float* root2  = (const float*)d_in[8];
  const float* b2     = (const float*)d_in[9];
  const float* fcw    = (const float*)d_in[10];
  const float* fcb    = (const float*)d_in[11];
  float* out = (float*)d_out;

  char* ws = (char*)d_ws;
  int*      cnt    = (int*)ws;                                    // N ints
  int2*     bucket = (int2*)(cnt + N_NODES);                      // N*CAP int2 (26.2 MB)
  unsigned* h1h    = (unsigned*)(bucket + (size_t)N_NODES * CAP); // N*16 dwords (fp16 h1)
  float*    gbuf   = (float*)(h1h + (size_t)N_NODES * 16);        // 64*64 fp32
  unsigned* xh     = (unsigned*)(gbuf + 64 * 64);                 // N*4 dwords (fp16 x)
  __half*   W1T    = (__half*)(xh + (size_t)N_NODES * 4);         // 32*224
  __half*   W2T    = W1T + 32 * 224;                              // 64*832

  hipMemsetAsync(cnt, 0, N_NODES * sizeof(int), stream);

  prep<<<1852, 256, 0, stream>>>(x, W1, root1, W2, root2,
                                 (__half*)xh, W1T, W2T, gbuf);
  scatter_eid<<<N_EDGES / 2048, 256, 0, stream>>>(ei, pseudo, cnt, bucket);
  fused_l1<<<N_NODES / L1N, 256, 0, stream>>>(bucket, cnt, xh, W1T, b1,
                                              (unsigned short*)h1h);
  fused_l2<<<N_NODES / L2N, 256, 0, stream>>>(bucket, cnt, h1h, W2T, b2, gbuf);
  fc_ls<<<NB, 64, 0, stream>>>(gbuf, slices, fcw, fcb, out);
}

// Round 5
// 215.786 us; speedup vs baseline: 4.0794x; 1.3803x over previous
//
#include <hip/hip_runtime.h>
#include <hip/hip_fp16.h>
#include <math.h>

#define N_NODES 51200
#define N_EDGES 819200
#define NB 64
#define CAP 64  // max in-degree; Binomial(E,1/N) mean 16, P(>=64) ~ 1e-19

typedef _Float16 half8 __attribute__((ext_vector_type(8)));
typedef __attribute__((ext_vector_type(4))) float float4v;
typedef __attribute__((ext_vector_type(16))) float float16v;

__device__ __forceinline__ float eluf(float x) {
  return x > 0.f ? x : expm1f(x);
}

// Decode packed edge record {w0 = src|K<<16, w1 = half2(f0,f1)} for corner c.
__device__ __forceinline__ void dec2(int w0, int w1, int c, float& basf, int& Kc) {
  int K = w0 >> 16;  // src < 65536, K <= 18 -> w0 >= 0
  float f0 = __half2float(__ushort_as_half((unsigned short)(w1 & 0xFFFF)));
  float f1 = __half2float(__ushort_as_half((unsigned short)(((unsigned)w1) >> 16)));
  float b0 = (c & 2) ? f0 : 1.f - f0;
  float bv = (c & 1) ? f1 : 1.f - f1;
  Kc = K + (c >> 1) * 5 + (c & 1);
  basf = b0 * bv;
}

// Prep: xcast (N x 7 fp32 -> N x 8 fp16) | W1T | W2T | zero gbuf. Grid 1852.
__global__ __launch_bounds__(256) void prep(const float* __restrict__ x,
                                            const float* __restrict__ W1,
                                            const float* __restrict__ root1,
                                            const float* __restrict__ W2,
                                            const float* __restrict__ root2,
                                            __half* __restrict__ xh,
                                            __half* __restrict__ W1T,
                                            __half* __restrict__ W2T,
                                            float* __restrict__ gbuf) {
  int b = blockIdx.x, tid = threadIdx.x;
  if (b < 1600) {                       // xcast: N*8 = 409600
    int idx = b * 256 + tid;
    int n = idx >> 3, j = idx & 7;
    xh[idx] = __float2half((j < 7) ? x[n * 7 + j] : 0.f);
  } else if (b < 1628) {                // W1T: 32 feats x 224 = 7168
    int idx = (b - 1600) * 256 + tid;
    int o = idx / 224, k = idx - o * 224;
    float v = 0.f;
    if (k < 200) {
      int cell = k >> 3, f = k & 7;
      if (f < 7) v = W1[(cell * 7 + f) * 32 + o];
    } else if (k < 207) {
      v = root1[(k - 200) * 32 + o];
    }
    W1T[idx] = __float2half(v);
  } else if (b < 1836) {                // W2T: 64 feats x 832 = 53248
    int idx = (b - 1628) * 256 + tid;
    int o = idx / 832, k = idx - o * 832;
    float v = (k < 800) ? W2[k * 64 + o] : root2[(k - 800) * 64 + o];
    W2T[idx] = __float2half(v);
  } else {                              // zero gbuf: 64*64 = 4096
    int idx = (b - 1836) * 256 + tid;
    gbuf[idx] = 0.f;
  }
}

// Build dst-CSR with fixed-capacity buckets; 8 edges per thread (8 independent
// atomic chains in flight). cnt doubles as degree.
__global__ __launch_bounds__(256) void scatter_eid(const int* __restrict__ ei,
                                                   const float* __restrict__ pseudo,
                                                   int* __restrict__ cnt,
                                                   int2* __restrict__ bucket) {
  int base = blockIdx.x * 2048 + threadIdx.x;
#pragma unroll
  for (int u = 0; u < 8; u++) {
    int e = base + u * 256;
    int src = ei[e], dst = ei[N_EDGES + e];
    float v0 = pseudo[2 * e] * 4.f;
    float v1 = pseudo[2 * e + 1] * 4.f;
    int lo0 = min(max((int)floorf(v0), 0), 3);
    int lo1 = min(max((int)floorf(v1), 0), 3);
    float f0 = v0 - (float)lo0, f1 = v1 - (float)lo1;
    int K = lo0 * 5 + lo1;  // corners at K, K+1, K+5, K+6
    unsigned short u0 = __half_as_ushort(__float2half(f0));
    unsigned short u1 = __half_as_ushort(__float2half(f1));
    int w0 = src | (K << 16);
    int w1 = (int)((unsigned)u0 | ((unsigned)u1 << 16));
    int slot = atomicAdd(&cnt[dst], 1);
    if (slot < CAP) bucket[(size_t)dst * CAP + slot] = make_int2(w0, w1);
  }
}

// Layer 1 fused (R0 proven form): T[16 nodes][224 halves] in LDS; Phase A:
// 4 nodes in parallel per wave (lane = slot|corner|pair), software-pipelined
// edge loop (records prefetched 2 iters ahead, x-gathers 1 iter ahead);
// serialized half2 LDS RMW (REQUIRED ordering: different edges can alias the
// same cell); then MFMA f16:
// h1 = elu( ([T | deg*x] @ [W1;root1]T) * invdeg + b1 ), fp16 out.
#define L1N 16
__global__ __launch_bounds__(256) void fused_l1(const int2* __restrict__ bucket,
                                                const int* __restrict__ cnt,
                                                const unsigned* __restrict__ xh,   // N x 4 dwords
                                                const __half* __restrict__ W1T,
                                                const float* __restrict__ b1,
                                                unsigned short* __restrict__ h1h) {
  __shared__ unsigned T[L1N * 112];  // 7.2 KB
  __shared__ float invdeg_s[L1N];
  int tid = threadIdx.x;
  int n0 = blockIdx.x * L1N;
  for (int idx = tid; idx < L1N * 112; idx += 256) T[idx] = 0u;
  if (tid < L1N) invdeg_s[tid] = 1.f / fmaxf((float)cnt[n0 + tid], 1.f);
  __syncthreads();
  // append max(deg,1)*x at dwords 100..103 (Phase A touches dwords < 100).
  if (tid < L1N * 4) {
    int row = tid >> 2, p = tid & 3;
    int n = n0 + row;
    float dgc = fmaxf((float)cnt[n], 1.f);
    unsigned xv = xh[n * 4 + p];
    __half2 h = __hmul2(*(const __half2*)&xv, __float2half2_rn(dgc));
    T[row * 112 + 100 + p] = *(unsigned*)&h;
  }
  int wv = tid >> 6, l = tid & 63;
  int slot = l >> 4, c = (l >> 2) & 3, p = l & 3;
  int nn = wv * 4 + slot;
  int n = n0 + nn;
  int dg = min(cnt[n], CAP);
  int dmax = dg;
  dmax = max(dmax, __shfl_xor(dmax, 16));
  dmax = max(dmax, __shfl_xor(dmax, 32));
  const int2* bk = bucket + (size_t)n * CAP;
  unsigned* Tr = &T[nn * 112];
  // pipeline prologue: records for iters 0,1; x-gathers for iter 0.
  int4 ra0 = *(const int4*)(bk + 0);
  int4 rb0 = *(const int4*)(bk + 2);
  int4 ra1 = *(const int4*)(bk + 4);
  int4 rb1 = *(const int4*)(bk + 6);
  unsigned xv0 = xh[(ra0.x & 0xFFFF) * 4 + p];
  unsigned xv1 = xh[(ra0.z & 0xFFFF) * 4 + p];
  unsigned xv2 = xh[(rb0.x & 0xFFFF) * 4 + p];
  unsigned xv3 = xh[(rb0.z & 0xFFFF) * 4 + p];
  for (int j = 0; j < dmax; j += 4) {
    int jp = min(j + 8, CAP - 4);               // records 2 iters ahead
    int4 ra2 = *(const int4*)(bk + jp);
    int4 rb2 = *(const int4*)(bk + jp + 2);
    unsigned nx0 = xh[(ra1.x & 0xFFFF) * 4 + p];  // gathers 1 iter ahead
    unsigned nx1 = xh[(ra1.z & 0xFFFF) * 4 + p];
    unsigned nx2 = xh[(rb1.x & 0xFFFF) * 4 + p];
    unsigned nx3 = xh[(rb1.z & 0xFFFF) * 4 + p];
    bool a0 = j < dg, a1 = j + 1 < dg, a2 = j + 2 < dg, a3 = j + 3 < dg;
    float bf; int Kc;
    if (a0) { dec2(ra0.x, ra0.y, c, bf, Kc);
      __half2* tp = (__half2*)&Tr[Kc * 4 + p];
      *tp = __hfma2(__float2half2_rn(bf), *(const __half2*)&xv0, *tp); }
    if (a1) { dec2(ra0.z, ra0.w, c, bf, Kc);
      __half2* tp = (__half2*)&Tr[Kc * 4 + p];
      *tp = __hfma2(__float2half2_rn(bf), *(const __half2*)&xv1, *tp); }
    if (a2) { dec2(rb0.x, rb0.y, c, bf, Kc);
      __half2* tp = (__half2*)&Tr[Kc * 4 + p];
      *tp = __hfma2(__float2half2_rn(bf), *(const __half2*)&xv2, *tp); }
    if (a3) { dec2(rb0.z, rb0.w, c, bf, Kc);
      __half2* tp = (__half2*)&Tr[Kc * 4 + p];
      *tp = __hfma2(__float2half2_rn(bf), *(const __half2*)&xv3, *tp); }
    ra0 = ra1; rb0 = rb1; ra1 = ra2; rb1 = rb2;
    xv0 = nx0; xv1 = nx1; xv2 = nx2; xv3 = nx3;
  }
  __syncthreads();
  // MFMA: waves 0,1 -> feat tiles 0,1; M=16 nodes, K=224 (7 iters).
  if (wv < 2) {
    int m = l & 15, quad = l >> 4;
    const char* abase = (const char*)T + m * 448 + quad * 16;
    const __half* bbase = W1T + (wv * 16 + m) * 224 + quad * 8;
    float4v acc = {0.f, 0.f, 0.f, 0.f};
#pragma unroll
    for (int it = 0; it < 7; it++) {
      half8 af = *(const half8*)(abase + it * 64);
      half8 bf = *(const half8*)(bbase + it * 32);
      acc = __builtin_amdgcn_mfma_f32_16x16x32_f16(af, bf, acc, 0, 0, 0);
    }
    int feat = wv * 16 + m;
    float bb = b1[feat];
#pragma unroll
    for (int r = 0; r < 4; r++) {
      int row = quad * 4 + r;
      float v = eluf(acc[r] * invdeg_s[row] + bb);
      h1h[(size_t)(n0 + row) * 32 + feat] = __half_as_ushort(__float2half(v));
    }
  }
}

// Layer 2 fused — R4: Phase A as MFMA outer-product. Per node n:
//   T(25x32) = A(25 cells x 16 edges weights) . B(16 edges x 32 feats h1)
// one mfma_f32_32x32x16_f16 per 16-edge chunk, fp32 accumulation in AGPRs.
// No LDS RMW chain (R0's bottleneck), no per-cell VALU redundancy (R3's).
// A built by collision-free scatter (corners of one edge = distinct cells;
// distinct edges = distinct rows). B staged coalesced 16B/lane. Chunk queue
// (4 nodes x 1..4 chunks, uniform walkers) pipelines records 2 chunks ahead
// and B-gathers 1 ahead. Fragment mapping (canonical gfx950, matches the
// proven 16x16x32 pattern): A/B lane holds [row|col = l&31][k=(l>>5)*8+i];
// C/D: col = l&31, row = (reg&3)+8*(reg>>2)+4*(l>>5).
#define L2N 16
__global__ __launch_bounds__(256) void fused_l2(const int2* __restrict__ bucket,
                                                const int* __restrict__ cnt,
                                                const unsigned* __restrict__ h1hu,  // N x 16 dwords
                                                const __half* __restrict__ W2T,
                                                const float* __restrict__ b2,
                                                float* __restrict__ gbuf) {
  __shared__ unsigned T16[L2N * 420];   // 26.9 KB; [row][420 dwords]
  __shared__ __half AB[4][2][512];      // per-wave A,B stages (8 KB)
  __shared__ float invdeg_s[L2N];
  int tid = threadIdx.x;
  int n0 = blockIdx.x * L2N;
  if (tid < L2N) invdeg_s[tid] = 1.f / fmaxf((float)cnt[n0 + tid], 1.f);
  // zero pad dwords 416..419 (read by Phase B K-range, never written below)
  if (tid < L2N * 4) T16[(tid >> 2) * 420 + 416 + (tid & 3)] = 0u;
  // append max(deg,1)*h1 at dwords 400..415 (writeback touches halves < 800).
  {
    int row = tid >> 4, p = tid & 15;
    int n = n0 + row;
    float dgc = fmaxf((float)cnt[n], 1.f);
    unsigned hv = h1hu[(size_t)n * 16 + p];
    __half2 h = __hmul2(*(const __half2*)&hv, __float2half2_rn(dgc));
    T16[row * 420 + 400 + p] = *(unsigned*)&h;
  }
  int wv = tid >> 6, l = tid & 63;
  _Float16* Ast = (_Float16*)AB[wv][0];
  _Float16* Bst = (_Float16*)AB[wv][1];
  int eL = l >> 2, cL = l & 3;        // staging roles: edge-in-chunk, corner
  int col = l & 31, kg = l >> 5;      // fragment roles
  int b0c = cL >> 1, b1c = cL & 1;    // corner bits
  // per-node degrees & chunk counts (wave-uniform), packed to avoid arrays
  int nb = n0 + wv * 4;
  int dg0 = min(cnt[nb + 0], CAP), dg1 = min(cnt[nb + 1], CAP);
  int dg2 = min(cnt[nb + 2], CAP), dg3 = min(cnt[nb + 3], CAP);
  int nc0 = max(1, (dg0 + 15) >> 4), nc1 = max(1, (dg1 + 15) >> 4);
  int nc2 = max(1, (dg2 + 15) >> 4), nc3 = max(1, (dg3 + 15) >> 4);
  int Q = nc0 + nc1 + nc2 + nc3;
  unsigned dgpack = (unsigned)dg0 | ((unsigned)dg1 << 7) |
                    ((unsigned)dg2 << 14) | ((unsigned)dg3 << 21);
  unsigned ncpack = (unsigned)nc0 | ((unsigned)nc1 << 4) |
                    ((unsigned)nc2 << 8) | ((unsigned)nc3 << 12);
  const int2* bkb = bucket + (size_t)nb * CAP;
#define NCH(s) ((int)((ncpack >> ((s) * 4)) & 15))
#define DGD(s) ((int)((dgpack >> ((s) * 7)) & 127))
#define ADV(S, T) do { if ((T) + 1 < NCH(S)) (T)++; \
                       else if ((S) < 3) { (S)++; (T) = 0; } } while (0)
  int s0 = 0, t0 = 0, s1 = 0, t1 = 0, s2 = 0, t2 = 0;
  ADV(s1, t1);
  ADV(s2, t2); ADV(s2, t2);
  // prologue: records for chunks 0,1; B-gather for chunk 0.
  int2 rec0 = bkb[s0 * CAP + t0 * 16 + eL];
  int2 rec1 = bkb[s1 * CAP + t1 * 16 + eL];
  int src0i = ((t0 * 16 + eL) < DGD(s0)) ? (rec0.x & 0xFFFF) : 0;
  int4 Breg0 = *(const int4*)(h1hu + (size_t)src0i * 16 + cL * 4);
  float16v acc = {};
  for (int q = 0; q < Q; q++) {
    // issue record(q+2) and B-gather(q+1); walkers clamp at end (dup loads ok)
    int2 rec2 = bkb[s2 * CAP + t2 * 16 + eL];
    int src1i = ((t1 * 16 + eL) < DGD(s1)) ? (rec1.x & 0xFFFF) : 0;
    int4 Breg1 = *(const int4*)(h1hu + (size_t)src1i * 16 + cL * 4);
    // current chunk: corner weight for (edge eL, corner cL)
    bool ein = (t0 * 16 + eL) < DGD(s0);
    int K = rec0.x >> 16;
    float f0 = __half2float(__ushort_as_half((unsigned short)(rec0.y & 0xFFFF)));
    float f1 = __half2float(__ushort_as_half((unsigned short)(((unsigned)rec0.y) >> 16)));
    float w = (b0c ? f0 : 1.f - f0) * (b1c ? f1 : 1.f - f1);
    int cell = K + b0c * 5 + b1c;
    // A stage: zero 1KB (16B/lane), then collision-free scatter of weights
    *(int4*)((char*)Ast + l * 16) = make_int4(0, 0, 0, 0);
    if (ein) Ast[eL * 32 + cell] = (_Float16)w;
    // B stage: [edge][feat] row-major; lane writes its 16B chunk
    *(int4*)((char*)Bst + l * 16) = Breg0;
    // fragments (in-order LDS per wave: reads see the writes above)
    half8 af, bf;
#pragma unroll
    for (int i = 0; i < 8; i++) {
      af[i] = Ast[(kg * 8 + i) * 32 + col];
      bf[i] = Bst[(kg * 8 + i) * 32 + col];
    }
    acc = __builtin_amdgcn_mfma_f32_32x32x16_f16(af, bf, acc, 0, 0, 0);
    // node complete -> writeback C rows (cells) < 25 to T16, reset acc
    if (t0 == NCH(s0) - 1) {
      __half* Trow = (__half*)&T16[(wv * 4 + s0) * 420];
#pragma unroll
      for (int r = 0; r < 16; r++) {
        int crow = (r & 3) + 8 * (r >> 2) + 4 * kg;
        if (crow < 25) Trow[crow * 32 + col] = __float2half(acc[r]);
      }
      acc = (float16v){};
      if (s0 < 3) { s0++; t0 = 0; }
    } else {
      t0++;
    }
    rec0 = rec1; rec1 = rec2; Breg0 = Breg1;
    ADV(s1, t1);
    ADV(s2, t2);
  }
  __syncthreads();
  // Phase B (unchanged): wave wv -> feats [wv*16, wv*16+16), K=832 (26 iters).
  int m = l & 15, quad = l >> 4;
  const char* abase = (const char*)T16 + m * 1680 + quad * 16;
  const __half* bbase = W2T + (size_t)(wv * 16 + m) * 832 + quad * 8;
  float4v acc2 = {0.f, 0.f, 0.f, 0.f};
  for (int it = 0; it < 26; it++) {
    half8 a2 = *(const half8*)(abase + it * 64);
    half8 b2f = *(const half8*)(bbase + it * 32);
    acc2 = __builtin_amdgcn_mfma_f32_16x16x32_f16(a2, b2f, acc2, 0, 0, 0);
  }
  int feat = wv * 16 + m;
  float bb = b2[feat];
  float psum = 0.f;
#pragma unroll
  for (int r = 0; r < 4; r++) {
    int node = quad * 4 + r;
    psum += eluf(acc2[r] * invdeg_s[node] + bb);
  }
  // reduce over quad (nodes) -> full 16-node sum per feat; 800 nodes per
  // group and 800 % L2N == 0, so the whole block is in one group.
  psum += __shfl_xor(psum, 16);
  psum += __shfl_xor(psum, 32);
  if (l < 16) {
    int g = n0 / 800;
    atomicAdd(&gbuf[g * 64 + feat], psum);
  }
}

// FC(64->30) + log_softmax on pooled sums. gbuf holds per-group SUM of elu(h2);
// divide by slice count here. One block (64 thr) per group; lanes 0..29 active.
__global__ __launch_bounds__(64) void fc_ls(const float* __restrict__ gbuf,
                                            const int* __restrict__ slices,
                                            const float* __restrict__ fcw,
                                            const float* __restrict__ fcb,
                                            float* __restrict__ out) {
  int g = blockIdx.x;
  int l = threadIdx.x;
  float scale = 1.f / fmaxf((float)(slices[g + 1] - slices[g]), 1.f);
  float logit = -INFINITY;
  if (l < 30) {
    float acc = fcb[l];
    for (int i = 0; i < 64; i++) acc += gbuf[g * 64 + i] * scale * fcw[i * 30 + l];
    logit = acc;
  }
  float m = logit;
  for (int off = 16; off; off >>= 1) m = fmaxf(m, __shfl_xor(m, off, 32));
  float e = (l < 30) ? expf(logit - m) : 0.f;
  for (int off = 16; off; off >>= 1) e += __shfl_xor(e, off, 32);
  if (l < 30) out[g * 30 + l] = logit - m - logf(e);
}

extern "C" void kernel_launch(void* const* d_in, const int* in_sizes, int n_in,
                              void* d_out, int out_size, void* d_ws, size_t ws_size,
                              hipStream_t stream) {
  const float* x      = (const float*)d_in[0];
  const int*   ei     = (const int*)d_in[1];
  const float* pseudo = (const float*)d_in[2];
  const int*   slices = (const int*)d_in[3];
  const float* W1     = (const float*)d_in[4];
  const float* root1  = (const float*)d_in[5];
  const float* b1     = (const float*)d_in[6];
  const float* W2     = (const float*)d_in[7];
  const float* root2  = (const float*)d_in[8];
  const float* b2     = (const float*)d_in[9];
  const float* fcw    = (const float*)d_in[10];
  const float* fcb    = (const float*)d_in[11];
  float* out = (float*)d_out;

  char* ws = (char*)d_ws;
  int*      cnt    = (int*)ws;                                    // N ints
  int2*     bucket = (int2*)(cnt + N_NODES);                      // N*CAP int2 (26.2 MB)
  unsigned* h1h    = (unsigned*)(bucket + (size_t)N_NODES * CAP); // N*16 dwords (fp16 h1)
  float*    gbuf   = (float*)(h1h + (size_t)N_NODES * 16);        // 64*64 fp32
  unsigned* xh     = (unsigned*)(gbuf + 64 * 64);                 // N*4 dwords (fp16 x)
  __half*   W1T    = (__half*)(xh + (size_t)N_NODES * 4);         // 32*224
  __half*   W2T    = W1T + 32 * 224;                              // 64*832

  hipMemsetAsync(cnt, 0, N_NODES * sizeof(int), stream);

  prep<<<1852, 256, 0, stream>>>(x, W1, root1, W2, root2,
                                 (__half*)xh, W1T, W2T, gbuf);
  scatter_eid<<<N_EDGES / 2048, 256, 0, stream>>>(ei, pseudo, cnt, bucket);
  fused_l1<<<N_NODES / L1N, 256, 0, stream>>>(bucket, cnt, xh, W1T, b1,
                                              (unsigned short*)h1h);
  fused_l2<<<N_NODES / L2N, 256, 0, stream>>>(bucket, cnt, h1h, W2T, b2, gbuf);
  fc_ls<<<NB, 64, 0, stream>>>(gbuf, slices, fcw, fcb, out);
}